// Round 1
// baseline (46.994 us; speedup 1.0000x reference)
//
#include <hip/hip_runtime.h>

// Problem: z (8, 8192, 256) fp32; width=9 (runtime scalar input).
// out = z * exp(z) / denom, denom[b,n] = windowed (width) sum over n of
//       s[b,n] = sum_c exp(z[b,n,c]), zero-padded at row edges.

static constexpr int kB = 8;
static constexpr int kN = 8192;
static constexpr int kC = 256;          // channels, contiguous innermost
static constexpr int kRows = kB * kN;   // 65536
static constexpr int kRowsPerBlock = 4; // one 64-lane wave per row

// Pass A: per-row channel sum of exp(z). One wave (64 lanes) per row,
// float4 loads -> 4 exps/lane -> 64-lane shfl_xor reduce -> lane 0 stores.
__global__ void __launch_bounds__(256)
sum_exp_rows(const float* __restrict__ z, float* __restrict__ s) {
    const int row  = blockIdx.x * kRowsPerBlock + (threadIdx.x >> 6);
    const int lane = threadIdx.x & 63;
    const float4 v =
        reinterpret_cast<const float4*>(z + (size_t)row * kC)[lane];
    float e = __expf(v.x) + __expf(v.y) + __expf(v.z) + __expf(v.w);
#pragma unroll
    for (int off = 32; off >= 1; off >>= 1)
        e += __shfl_xor(e, off);
    if (lane == 0) s[row] = e;
}

// Pass B: per row compute denom (width broadcast loads of s, bounds-checked
// for the zero-pad edges), then out = z * exp(z) / denom vectorized float4.
__global__ void __launch_bounds__(256)
finalize(const float* __restrict__ z, const float* __restrict__ s,
         const int* __restrict__ wptr, float* __restrict__ out) {
    const int row  = blockIdx.x * kRowsPerBlock + (threadIdx.x >> 6);
    const int lane = threadIdx.x & 63;
    const int b = row / kN;
    const int n = row - b * kN;

    const int width = *wptr;     // scalar, L2-broadcast
    const int half  = width >> 1;

    const float* sb = s + (size_t)b * kN;
    float d = 0.0f;
    const int lo = n - half;
    for (int k = 0; k < width; ++k) {
        const int m = lo + k;
        if (m >= 0 && m < kN) d += sb[m];   // same addr across lanes: broadcast
    }
    const float rinv = 1.0f / d;

    const size_t base = (size_t)row * kC;
    const float4 v = reinterpret_cast<const float4*>(z + base)[lane];
    float4 o;
    o.x = v.x * __expf(v.x) * rinv;
    o.y = v.y * __expf(v.y) * rinv;
    o.z = v.z * __expf(v.z) * rinv;
    o.w = v.w * __expf(v.w) * rinv;
    reinterpret_cast<float4*>(out + base)[lane] = o;
}

extern "C" void kernel_launch(void* const* d_in, const int* in_sizes, int n_in,
                              void* d_out, int out_size, void* d_ws, size_t ws_size,
                              hipStream_t stream) {
    const float* z    = (const float*)d_in[0];
    const int*   wptr = (const int*)d_in[1];
    float*       out  = (float*)d_out;
    float*       s    = (float*)d_ws;   // kRows floats = 256 KiB scratch

    const int blocks = kRows / kRowsPerBlock;   // 16384
    sum_exp_rows<<<blocks, 256, 0, stream>>>(z, s);
    finalize<<<blocks, 256, 0, stream>>>(z, s, wptr, out);
}

// Round 2
// 29.851 us; speedup vs baseline: 1.5743x; 1.5743x over previous
//
#include <hip/hip_runtime.h>

// z (8, 8192, 256) fp32; width=9 (runtime scalar input, half=4).
// out = z * exp(z) / denom, denom[b,n] = width-window sum over n of
//       s[b,n] = sum_c exp(z[b,n,c]), zero-padded at batch-row edges.
//
// Fused single pass: block = 64 rows of one batch, z held in registers,
// per-row exp-sums (wave shuffle reduce) + 8 halo rows into LDS, one
// barrier, windowed denom from LDS broadcast reads, finalize from regs.

static constexpr int kB   = 8;
static constexpr int kN   = 8192;
static constexpr int kC   = 256;   // contiguous innermost
static constexpr int ROWS = 64;    // rows per block
static constexpr int HALO = 4;     // width 9 -> half 4
static constexpr int THREADS = 512; // 8 waves
static constexpr int RPW  = 8;     // rows per wave

__global__ void __launch_bounds__(THREADS)
fused_spatial_softmax(const float* __restrict__ z, const int* __restrict__ wptr,
                      float* __restrict__ out) {
    __shared__ float s_lds[ROWS + 2 * HALO];   // row exp-sums incl. halo

    const int wave = threadIdx.x >> 6;
    const int lane = threadIdx.x & 63;
    const int blocksPerBatch = kN / ROWS;              // 128
    const int b  = blockIdx.x / blocksPerBatch;
    const int n0 = (blockIdx.x % blocksPerBatch) * ROWS;

    const float* zb = z   + ((size_t)b * kN + n0) * kC;
    float*       ob = out + ((size_t)b * kN + n0) * kC;

    // ---- load this wave's 8 main rows into registers (coalesced float4) ----
    const int r0 = wave * RPW;
    float4 v[RPW];
#pragma unroll
    for (int i = 0; i < RPW; ++i)
        v[i] = reinterpret_cast<const float4*>(zb + (size_t)(r0 + i) * kC)[lane];

    // ---- one halo row per wave (redundant across neighbor blocks) ----
    {
        const int nrel = (wave < HALO) ? (wave - HALO) : (ROWS + wave - HALO);
        const int n = n0 + nrel;
        float e = 0.0f;                       // zero-pad outside the batch
        if (n >= 0 && n < kN) {
            const float4 hv = reinterpret_cast<const float4*>(
                z + ((size_t)b * kN + n) * kC)[lane];
            e = __expf(hv.x) + __expf(hv.y) + __expf(hv.z) + __expf(hv.w);
#pragma unroll
            for (int off = 32; off >= 1; off >>= 1) e += __shfl_xor(e, off);
        }
        if (lane == 0) s_lds[HALO + nrel] = e;
    }

    // ---- main row exp-sums: 64-lane shuffle reduce, lane 0 -> LDS ----
#pragma unroll
    for (int i = 0; i < RPW; ++i) {
        float e = __expf(v[i].x) + __expf(v[i].y) + __expf(v[i].z) + __expf(v[i].w);
#pragma unroll
        for (int off = 32; off >= 1; off >>= 1) e += __shfl_xor(e, off);
        if (lane == 0) s_lds[HALO + r0 + i] = e;
    }

    __syncthreads();

    const int width = *wptr;       // 9 in this problem
    const int half  = width >> 1;

    // ---- windowed denom (LDS broadcast reads) + finalize from registers ----
#pragma unroll
    for (int i = 0; i < RPW; ++i) {
        const int nrel = r0 + i;
        float d = 0.0f;
        const int base = HALO + nrel - half;
        for (int k = 0; k < width; ++k) d += s_lds[base + k];
        const float rinv = 1.0f / d;
        float4 o;
        o.x = v[i].x * __expf(v[i].x) * rinv;
        o.y = v[i].y * __expf(v[i].y) * rinv;
        o.z = v[i].z * __expf(v[i].z) * rinv;
        o.w = v[i].w * __expf(v[i].w) * rinv;
        reinterpret_cast<float4*>(ob + (size_t)nrel * kC)[lane] = o;
    }
}

extern "C" void kernel_launch(void* const* d_in, const int* in_sizes, int n_in,
                              void* d_out, int out_size, void* d_ws, size_t ws_size,
                              hipStream_t stream) {
    const float* z    = (const float*)d_in[0];
    const int*   wptr = (const int*)d_in[1];
    float*       out  = (float*)d_out;

    const int blocks = (kB * kN) / ROWS;   // 1024
    fused_spatial_softmax<<<blocks, THREADS, 0, stream>>>(z, wptr, out);
}

// Round 4
// 29.433 us; speedup vs baseline: 1.5966x; 1.0142x over previous
//
#include <hip/hip_runtime.h>

// z (8, 8192, 256) fp32; width=9 (runtime scalar input, half=4).
// out = z * exp(z) / denom, denom[b,n] = width-window sum over n of
//       s[b,n] = sum_c exp(z[b,n,c]), zero-padded at batch-row edges.
//
// Fused single pass: block = 128 rows of one batch (16 waves, 8 rows/wave),
// z*exp(z) precomputed into registers during phase 1 (no exp on store path),
// per-row exp-sums + 8 halo rows into LDS, one barrier, windowed denom from
// LDS broadcast reads, rcp + mul + non-temporal store.

typedef float f32x4 __attribute__((ext_vector_type(4)));   // clang vector: ok for nontemporal builtins

static constexpr int kB      = 8;
static constexpr int kN      = 8192;
static constexpr int kC      = 256;    // contiguous innermost
static constexpr int ROWS    = 128;    // rows per block
static constexpr int HALO    = 4;      // width 9 -> half 4
static constexpr int THREADS = 1024;   // 16 waves
static constexpr int WAVES   = THREADS / 64;
static constexpr int RPW     = ROWS / WAVES;   // 8 rows per wave

__global__ void __launch_bounds__(THREADS)
fused_spatial_softmax(const float* __restrict__ z, const int* __restrict__ wptr,
                      float* __restrict__ out) {
    __shared__ float s_lds[ROWS + 2 * HALO];   // 136 row exp-sums incl. halo

    const int wave = threadIdx.x >> 6;
    const int lane = threadIdx.x & 63;
    const int blocksPerBatch = kN / ROWS;              // 64
    const int b  = blockIdx.x / blocksPerBatch;
    const int n0 = (blockIdx.x % blocksPerBatch) * ROWS;

    const int width = *wptr;            // uniform; issue load early
    const int half  = width >> 1;

    const float* zb = z   + ((size_t)b * kN + n0) * kC;
    float*       ob = out + ((size_t)b * kN + n0) * kC;

    const int r0 = wave * RPW;

    // ---- halo: waves 0..7 each own one of the 8 halo rows ----
    if (wave < 2 * HALO) {
        const int nrel = (wave < HALO) ? (wave - HALO) : (ROWS + wave - HALO);
        const int n = n0 + nrel;
        float e = 0.0f;                 // zero-pad outside the batch
        if (n >= 0 && n < kN) {
            const f32x4 hv = reinterpret_cast<const f32x4*>(
                z + ((size_t)b * kN + n) * kC)[lane];
            e = __expf(hv.x) + __expf(hv.y) + __expf(hv.z) + __expf(hv.w);
#pragma unroll
            for (int off = 32; off >= 1; off >>= 1) e += __shfl_xor(e, off);
        }
        if (lane == 0) s_lds[HALO + nrel] = e;
    }

    // ---- main rows: exp-sum -> LDS; overwrite regs with w = z * exp(z) ----
    f32x4 w[RPW];
#pragma unroll
    for (int i = 0; i < RPW; ++i) {
        const f32x4 v = reinterpret_cast<const f32x4*>(zb + (size_t)(r0 + i) * kC)[lane];
        const float ex = __expf(v.x);
        const float ey = __expf(v.y);
        const float ez = __expf(v.z);
        const float ew = __expf(v.w);
        float e = ex + ey + ez + ew;
#pragma unroll
        for (int off = 32; off >= 1; off >>= 1) e += __shfl_xor(e, off);
        if (lane == 0) s_lds[HALO + r0 + i] = e;
        w[i].x = v.x * ex;
        w[i].y = v.y * ey;
        w[i].z = v.z * ez;
        w[i].w = v.w * ew;
    }

    __syncthreads();

    // ---- windowed denom (LDS broadcast reads) + finalize from registers ----
#pragma unroll
    for (int i = 0; i < RPW; ++i) {
        const int nrel = r0 + i;
        float d = 0.0f;
        const int base = HALO + nrel - half;
        for (int k = 0; k < width; ++k) d += s_lds[base + k];
        const float rinv = __builtin_amdgcn_rcpf(d);
        f32x4 o;
        o.x = w[i].x * rinv;
        o.y = w[i].y * rinv;
        o.z = w[i].z * rinv;
        o.w = w[i].w * rinv;
        __builtin_nontemporal_store(o,
            reinterpret_cast<f32x4*>(ob + (size_t)nrel * kC) + lane);
    }
}

extern "C" void kernel_launch(void* const* d_in, const int* in_sizes, int n_in,
                              void* d_out, int out_size, void* d_ws, size_t ws_size,
                              hipStream_t stream) {
    const float* z    = (const float*)d_in[0];
    const int*   wptr = (const int*)d_in[1];
    float*       out  = (float*)d_out;

    const int blocks = (kB * kN) / ROWS;   // 512
    fused_spatial_softmax<<<blocks, THREADS, 0, stream>>>(z, wptr, out);
}